// Round 3
// baseline (393.491 us; speedup 1.0000x reference)
//
#include <hip/hip_runtime.h>
#include <math.h>

// Output: 2 * pe[s][c] broadcast over batch (input fully discarded).
// 67,108,864 fp32 = 256 MiB pure streaming write. Roofline ~41 us @ 6.5 TB/s.

typedef float f4 __attribute__((ext_vector_type(4)));  // clang-native vector: OK for nontemporal builtin

__global__ __launch_bounds__(256) void pe_broadcast_kernel(f4* __restrict__ out, int total4) {
    const int tid = blockIdx.x * blockDim.x + threadIdx.x;

    // flat float index of this thread's first float4
    const int flat = tid * 4;
    const int s = (flat >> 4) & 63;   // position index 0..63
    const int p = flat & 15;          // first channel of this float4 (0,4,8,12)

    // Pattern period = 1024 floats; grid stride in floats (grid*256*4) is a
    // multiple of 1024, so each thread's value is loop-invariant: compute once.
    const float LOG2_10000_OVER_8 = 1.6609640474436813f; // log2(10000)/8
    f4 v;
#pragma unroll
    for (int k = 0; k < 4; ++k) {
        const int c = p + k;
        const float inv_freq = exp2f(-(float)c * LOG2_10000_OVER_8);
        const float div = (float)s * inv_freq;
        const float pe = ((c & 1) == 0) ? sinf(div) : cosf(div);
        v[k] = 2.0f * pe;
    }

    const int stride = gridDim.x * blockDim.x;  // 1,048,576 threads
    // 16 iterations per thread; unroll keeps >=4 stores in flight per thread.
#pragma unroll 4
    for (int i = tid; i < total4; i += stride) {
        __builtin_nontemporal_store(v, &out[i]);
    }
}

extern "C" void kernel_launch(void* const* d_in, const int* in_sizes, int n_in,
                              void* d_out, int out_size, void* d_ws, size_t ws_size,
                              hipStream_t stream) {
    (void)d_in; (void)in_sizes; (void)n_in; (void)d_ws; (void)ws_size;
    f4* out = (f4*)d_out;
    const int total4 = out_size / 4;           // 16,777,216 float4s
    const int block = 256;
    const int grid = 4096;                     // 1M threads, 16 float4 stores each
    pe_broadcast_kernel<<<grid, block, 0, stream>>>(out, total4);
}

// Round 4
// 381.454 us; speedup vs baseline: 1.0316x; 1.0316x over previous
//
#include <hip/hip_runtime.h>
#include <math.h>

// Output: 2 * pe[s][c] broadcast over batch; pe[s][c] = sin(div) if c even else cos(div),
// div = s / 10000^(c/16*2) = s * 2^(-c * log2(10000) / 8).
// Total output: 65536*64*16 = 67,108,864 fp32 = 256 MiB. Pure write, input unused.
// Write roofline: 268 MB / ~6.5 TB/s ≈ 41 us. Measured total dur (~381 us) is
// dominated by harness poison/restore fills (~165 us x2 visible in rocprof);
// our dispatch is below the top-5 cutoff (<163 us).
// R3 post-mortem: __builtin_nontemporal_store was neutral/slightly worse (393 vs 381) — reverted.

__global__ __launch_bounds__(256) void pe_broadcast_kernel(float4* __restrict__ out, int total4) {
    const int tid = blockIdx.x * blockDim.x + threadIdx.x;

    // flat float index of this thread's first float4
    const int flat = tid * 4;
    const int s = (flat >> 4) & 63;   // position index 0..63
    const int p = flat & 15;          // channel index of lane's first float (0,4,8,12)

    // Pattern period = 1024 floats; grid stride in floats (grid*256*4) is a
    // multiple of 1024, so each thread's value is loop-invariant: compute once.
    const float LOG2_10000_OVER_8 = 1.6609640474436813f; // log2(10000)/8
    float vals[4];
#pragma unroll
    for (int k = 0; k < 4; ++k) {
        const int c = p + k;
        const float inv_freq = exp2f(-(float)c * LOG2_10000_OVER_8);
        const float div = (float)s * inv_freq;
        const float pe = ((c & 1) == 0) ? sinf(div) : cosf(div);
        vals[k] = 2.0f * pe;
    }
    float4 v;
    v.x = vals[0]; v.y = vals[1]; v.z = vals[2]; v.w = vals[3];

    const int stride = gridDim.x * blockDim.x;
    for (int i = tid; i < total4; i += stride) {
        out[i] = v;
    }
}

extern "C" void kernel_launch(void* const* d_in, const int* in_sizes, int n_in,
                              void* d_out, int out_size, void* d_ws, size_t ws_size,
                              hipStream_t stream) {
    (void)d_in; (void)in_sizes; (void)n_in; (void)d_ws; (void)ws_size;
    float4* out = (float4*)d_out;
    const int total4 = out_size / 4;           // 16,777,216 float4s
    const int block = 256;
    // 2048 blocks * 256 threads = 524,288 threads (full residency); 32 stores/thread.
    const int grid = 2048;
    pe_broadcast_kernel<<<grid, block, 0, stream>>>(out, total4);
}